// Round 1
// baseline (289.685 us; speedup 1.0000x reference)
//
#include <hip/hip_runtime.h>

using short8 = __attribute__((ext_vector_type(8))) short;
using f32x4  = __attribute__((ext_vector_type(4))) float;

#define DEV __device__ __forceinline__

// float -> bf16 round-to-nearest-even (finite inputs)
DEV unsigned short f2bf(float f) {
    unsigned int u = __float_as_uint(f);
    u += 0x7fffu + ((u >> 16) & 1u);
    return (unsigned short)(u >> 16);
}

// ---------------------------------------------------------------- converts
__global__ __launch_bounds__(256) void cvt_k(const float* __restrict__ in,
                                             unsigned short* __restrict__ out, int n4) {
    int i = blockIdx.x * blockDim.x + threadIdx.x;
    int stride = gridDim.x * blockDim.x;
    for (; i < n4; i += stride) {
        float4 v = ((const float4*)in)[i];
        ushort4 o;
        o.x = f2bf(v.x); o.y = f2bf(v.y); o.z = f2bf(v.z); o.w = f2bf(v.w);
        ((ushort4*)out)[i] = o;
    }
}

// transpose + convert: in fp32 [R][C] -> out bf16 [C][R].  layerp: device scalar index
__global__ __launch_bounds__(256) void wt_k(const float* __restrict__ in,
                                            unsigned short* __restrict__ out,
                                            int R, int C,
                                            const int* __restrict__ layerp, int lstride) {
    if (layerp) in += (size_t)layerp[0] * (size_t)lstride;
    __shared__ float t[32][33];
    const int tx = threadIdx.x & 31, ty = threadIdx.x >> 5;
    const int c0 = blockIdx.x * 32, r0 = blockIdx.y * 32;
#pragma unroll
    for (int it = 0; it < 4; ++it)
        t[ty + it * 8][tx] = in[(size_t)(r0 + ty + it * 8) * C + c0 + tx];
    __syncthreads();
#pragma unroll
    for (int it = 0; it < 4; ++it)
        out[(size_t)(c0 + ty + it * 8) * R + r0 + tx] = f2bf(t[tx][ty + it * 8]);
}

// bf16 [b][2048][H*96] -> bf16 [b*H + h][96][2048]
__global__ __launch_bounds__(256) void kvt_k(const unsigned short* __restrict__ kv,
                                             unsigned short* __restrict__ kvT) {
    const int n0 = blockIdx.x * 32, d0 = blockIdx.y * 32, bh = blockIdx.z;
    const int b = bh >> 3, h = bh & 7;
    __shared__ unsigned short t[32][33];
    const int tx = threadIdx.x & 31, ty = threadIdx.x >> 5;
#pragma unroll
    for (int it = 0; it < 4; ++it)
        t[ty + it * 8][tx] = kv[(size_t)(b * 2048 + n0 + ty + it * 8) * 768 + h * 96 + d0 + tx];
    __syncthreads();
#pragma unroll
    for (int it = 0; it < 4; ++it)
        kvT[((size_t)bh * 96 + d0 + ty + it * 8) * 2048 + n0 + tx] = t[tx][ty + it * 8];
}

// ---------------------------------------------------------------- GEMM
// C[M,N] = A[M,K] * B^T  (B stored [N][K], k-contiguous).  128x128 tile, 4 waves 2x2,
// each wave 64x64 (4x4 frags of 16x16), BK=32.  LDS layout [kgroup][row128][8].
// EPI=0: write fp32.  EPI=1: add bias, write bf16.
template <int EPI>
__global__ __launch_bounds__(256) void gemm128(const unsigned short* __restrict__ A,
                                               const unsigned short* __restrict__ B,
                                               void* __restrict__ out,
                                               const float* __restrict__ bias,
                                               int K, int ldc) {
    __shared__ unsigned short smA[4096];
    __shared__ unsigned short smB[4096];
    const int tid = threadIdx.x, lane = tid & 63;
    const int l15 = lane & 15, g = lane >> 4;
    const int w = tid >> 6, wm = w >> 1, wn = w & 1;
    const int m0 = blockIdx.x * 128, n0 = blockIdx.y * 128;
    const int srow = tid >> 2, skg = tid & 3;  // staging: 64 rows x 4 kgroups per pass
    f32x4 acc[4][4] = {};
    const int nkt = K >> 5;
    for (int kt = 0; kt < nkt; ++kt) {
        const int k0 = kt << 5;
        __syncthreads();
        {
            short8 va0 = *(const short8*)(A + (size_t)(m0 + srow) * K + k0 + skg * 8);
            short8 va1 = *(const short8*)(A + (size_t)(m0 + 64 + srow) * K + k0 + skg * 8);
            short8 vb0 = *(const short8*)(B + (size_t)(n0 + srow) * K + k0 + skg * 8);
            short8 vb1 = *(const short8*)(B + (size_t)(n0 + 64 + srow) * K + k0 + skg * 8);
            *(short8*)(smA + (skg * 128 + srow) * 8) = va0;
            *(short8*)(smA + (skg * 128 + 64 + srow) * 8) = va1;
            *(short8*)(smB + (skg * 128 + srow) * 8) = vb0;
            *(short8*)(smB + (skg * 128 + 64 + srow) * 8) = vb1;
        }
        __syncthreads();
        short8 af[4], bf[4];
#pragma unroll
        for (int i = 0; i < 4; ++i)
            af[i] = *(const short8*)(smA + (g * 128 + wm * 64 + i * 16 + l15) * 8);
#pragma unroll
        for (int j = 0; j < 4; ++j)
            bf[j] = *(const short8*)(smB + (g * 128 + wn * 64 + j * 16 + l15) * 8);
#pragma unroll
        for (int i = 0; i < 4; ++i)
#pragma unroll
            for (int j = 0; j < 4; ++j)
                acc[i][j] = __builtin_amdgcn_mfma_f32_16x16x32_bf16(af[i], bf[j], acc[i][j], 0, 0, 0);
    }
#pragma unroll
    for (int j = 0; j < 4; ++j) {
        const int col = n0 + wn * 64 + j * 16 + l15;
        const float bv = (EPI == 1) ? bias[col] : 0.0f;
#pragma unroll
        for (int i = 0; i < 4; ++i)
#pragma unroll
            for (int r = 0; r < 4; ++r) {
                const int row = m0 + wm * 64 + i * 16 + g * 4 + r;
                const float v = acc[i][j][r] + bv;
                if (EPI == 0) ((float*)out)[(size_t)row * ldc + col] = v;
                else ((unsigned short*)out)[(size_t)row * ldc + col] = f2bf(v);
            }
    }
}

// ---------------------------------------------------------------- row norms
// one wave per 768-elem row
__global__ __launch_bounds__(256) void rownorm_k(const float* __restrict__ in,
                                                 float* __restrict__ outf,
                                                 unsigned short* __restrict__ outb) {
    const int lane = threadIdx.x & 63;
    const int row = blockIdx.x * 4 + (threadIdx.x >> 6);
    const float* p = in + (size_t)row * 768;
    float4 v[3];
    float s = 0.f;
#pragma unroll
    for (int i = 0; i < 3; ++i) {
        v[i] = ((const float4*)p)[i * 64 + lane];
        s += v[i].x * v[i].x + v[i].y * v[i].y + v[i].z * v[i].z + v[i].w * v[i].w;
    }
#pragma unroll
    for (int mask = 1; mask < 64; mask <<= 1) s += __shfl_xor(s, mask);
    const float inv = rsqrtf(s);
    float4* of = (float4*)(outf + (size_t)row * 768);
    ushort4* ob = (ushort4*)(outb + (size_t)row * 768);
#pragma unroll
    for (int i = 0; i < 3; ++i) {
        float4 q;
        q.x = v[i].x * inv; q.y = v[i].y * inv; q.z = v[i].z * inv; q.w = v[i].w * inv;
        of[i * 64 + lane] = q;
        ushort4 u;
        u.x = f2bf(q.x); u.y = f2bf(q.y); u.z = f2bf(q.z); u.w = f2bf(q.w);
        ob[i * 64 + lane] = u;
    }
}

__global__ __launch_bounds__(256) void resid_norm_k(const float* __restrict__ in,
                                                    const float* __restrict__ res,
                                                    float* __restrict__ outf) {
    const int lane = threadIdx.x & 63;
    const int row = blockIdx.x * 4 + (threadIdx.x >> 6);
    const float4* pa = (const float4*)(in + (size_t)row * 768);
    const float4* pb = (const float4*)(res + (size_t)row * 768);
    float4 v[3];
    float s = 0.f;
#pragma unroll
    for (int i = 0; i < 3; ++i) {
        float4 a = pa[i * 64 + lane];
        float4 b = pb[i * 64 + lane];
        float4 c;
        c.x = a.x + b.x; c.y = a.y + b.y; c.z = a.z + b.z; c.w = a.w + b.w;
        v[i] = c;
        s += c.x * c.x + c.y * c.y + c.z * c.z + c.w * c.w;
    }
#pragma unroll
    for (int mask = 1; mask < 64; mask <<= 1) s += __shfl_xor(s, mask);
    const float inv = rsqrtf(s);
    float4* of = (float4*)(outf + (size_t)row * 768);
#pragma unroll
    for (int i = 0; i < 3; ++i) {
        float4 q;
        q.x = v[i].x * inv; q.y = v[i].y * inv; q.z = v[i].z * inv; q.w = v[i].w * inv;
        of[i * 64 + lane] = q;
    }
}

// ---------------------------------------------------------------- fused attention
// grid = B*H*(2048/128); 4 waves x 32 q-rows.  KV chunk = 32.  Online softmax.
#define SCALE_F 0.036084391824351615f

__global__ __launch_bounds__(256) void attn_k(const unsigned short* __restrict__ Q,
                                              const unsigned short* __restrict__ KV,
                                              const unsigned short* __restrict__ KVT,
                                              float* __restrict__ O) {
    const int bid = blockIdx.x;
    const int qb = bid & 15, h = (bid >> 4) & 7, b = bid >> 7;
    const int tid = threadIdx.x, lane = tid & 63, w = tid >> 6;
    const int l15 = lane & 15, g = lane >> 4;
    const int q0 = qb * 128 + w * 32;
    __shared__ unsigned short plds[4][32][40];  // +8 pad: 80B rows -> 2-way max on b128 reads
    unsigned short(*pw)[40] = plds[w];

    short8 aq[2][3];
#pragma unroll
    for (int mi = 0; mi < 2; ++mi) {
        const unsigned short* qp = Q + (size_t)(b * 2048 + q0 + mi * 16 + l15) * 768 + h * 96 + g * 8;
#pragma unroll
        for (int ks = 0; ks < 3; ++ks) aq[mi][ks] = *(const short8*)(qp + ks * 32);
    }
    f32x4 o[2][6] = {};
    float m[2][4], l[2][4];
#pragma unroll
    for (int mi = 0; mi < 2; ++mi)
#pragma unroll
        for (int r = 0; r < 4; ++r) { m[mi][r] = -__builtin_inff(); l[mi][r] = 0.f; }

    const unsigned short* kb = KV + (size_t)(b * 2048) * 768 + h * 96;
    const unsigned short* vb = KVT + (size_t)((b * 8 + h) * 96) * 2048;

    for (int c = 0; c < 64; ++c) {
        const int n2 = c * 32;
        f32x4 s[2][2];
#pragma unroll
        for (int t = 0; t < 2; ++t) {
            const unsigned short* kp = kb + (size_t)(n2 + t * 16 + l15) * 768 + g * 8;
            short8 bk0 = *(const short8*)(kp);
            short8 bk1 = *(const short8*)(kp + 32);
            short8 bk2 = *(const short8*)(kp + 64);
#pragma unroll
            for (int mi = 0; mi < 2; ++mi) {
                f32x4 a = {};
                a = __builtin_amdgcn_mfma_f32_16x16x32_bf16(aq[mi][0], bk0, a, 0, 0, 0);
                a = __builtin_amdgcn_mfma_f32_16x16x32_bf16(aq[mi][1], bk1, a, 0, 0, 0);
                a = __builtin_amdgcn_mfma_f32_16x16x32_bf16(aq[mi][2], bk2, a, 0, 0, 0);
                s[mi][t] = a * SCALE_F;
            }
        }
#pragma unroll
        for (int mi = 0; mi < 2; ++mi) {
            float cm[4], al[4], rs[4];
#pragma unroll
            for (int r = 0; r < 4; ++r) cm[r] = fmaxf(s[mi][0][r], s[mi][1][r]);
#pragma unroll
            for (int mask = 1; mask < 16; mask <<= 1)
#pragma unroll
                for (int r = 0; r < 4; ++r) cm[r] = fmaxf(cm[r], __shfl_xor(cm[r], mask));
#pragma unroll
            for (int r = 0; r < 4; ++r) {
                const float nm = fmaxf(m[mi][r], cm[r]);
                al[r] = __expf(m[mi][r] - nm);
                m[mi][r] = nm;
                const float p0 = __expf(s[mi][0][r] - nm);
                const float p1 = __expf(s[mi][1][r] - nm);
                s[mi][0][r] = p0; s[mi][1][r] = p1;
                rs[r] = p0 + p1;
            }
#pragma unroll
            for (int mask = 1; mask < 16; mask <<= 1)
#pragma unroll
                for (int r = 0; r < 4; ++r) rs[r] += __shfl_xor(rs[r], mask);
#pragma unroll
            for (int r = 0; r < 4; ++r) l[mi][r] = l[mi][r] * al[r] + rs[r];
#pragma unroll
            for (int dt = 0; dt < 6; ++dt)
#pragma unroll
                for (int r = 0; r < 4; ++r) o[mi][dt][r] *= al[r];
#pragma unroll
            for (int t = 0; t < 2; ++t)
#pragma unroll
                for (int r = 0; r < 4; ++r)
                    pw[mi * 16 + g * 4 + r][t * 16 + l15] = f2bf(s[mi][t][r]);
        }
        short8 pa[2];
#pragma unroll
        for (int mi = 0; mi < 2; ++mi)
            pa[mi] = *(const short8*)&pw[mi * 16 + l15][g * 8];
#pragma unroll
        for (int dt = 0; dt < 6; ++dt) {
            short8 bv = *(const short8*)(vb + (size_t)(dt * 16 + l15) * 2048 + n2 + g * 8);
#pragma unroll
            for (int mi = 0; mi < 2; ++mi)
                o[mi][dt] = __builtin_amdgcn_mfma_f32_16x16x32_bf16(pa[mi], bv, o[mi][dt], 0, 0, 0);
        }
    }
#pragma unroll
    for (int mi = 0; mi < 2; ++mi)
#pragma unroll
        for (int r = 0; r < 4; ++r) {
            const float inv = 1.0f / l[mi][r];
            float* op = O + (size_t)(b * 2048 + q0 + mi * 16 + g * 4 + r) * 768 + h * 96 + l15;
#pragma unroll
            for (int dt = 0; dt < 6; ++dt) op[dt * 16] = o[mi][dt][r] * inv;
        }
}

// ---------------------------------------------------------------- launch
extern "C" void kernel_launch(void* const* d_in, const int* in_sizes, int n_in,
                              void* d_out, int out_size, void* d_ws, size_t ws_size,
                              hipStream_t stream) {
    const float* Ft = (const float*)d_in[0];   // [4,2048,768]
    const float* Fs = (const float*)d_in[1];   // [4,2048,1024]
    const float* Wl = (const float*)d_in[2];   // [4,1024,768]
    const float* Wq = (const float*)d_in[3];   // [768,768]
    const float* bq = (const float*)d_in[4];   // [768]
    const int* layer = (const int*)d_in[5];    // scalar

    float* out0 = (float*)d_out;               // F_t_a [4,2048,768]
    float* out1 = out0 + 6291456;              // F_s_p [4,2048,768]

    char* ws = (char*)d_ws;
    unsigned short* wsFs  = (unsigned short*)(ws);              // 16,777,216 B (reused for q after gemm1)
    unsigned short* wsFt  = (unsigned short*)(ws + 16777216);   // 12,582,912
    unsigned short* wsWlt = (unsigned short*)(ws + 29360128);   //  1,572,864
    unsigned short* wsWqt = (unsigned short*)(ws + 30932992);   //  1,179,648
    unsigned short* wsKV  = (unsigned short*)(ws + 32112640);   // 12,582,912
    unsigned short* wsKVT = (unsigned short*)(ws + 44695552);   // 12,582,912
    float*          wsTmp = (float*)(ws + 57278464);            // 25,165,824 (end ~82.4 MB)
    unsigned short* wsQ   = wsFs;

    cvt_k<<<2048, 256, 0, stream>>>(Fs, wsFs, 8388608 / 4);
    cvt_k<<<2048, 256, 0, stream>>>(Ft, wsFt, 6291456 / 4);
    wt_k<<<dim3(768 / 32, 1024 / 32), 256, 0, stream>>>(Wl, wsWlt, 1024, 768, layer, 1024 * 768);
    wt_k<<<dim3(768 / 32, 768 / 32), 256, 0, stream>>>(Wq, wsWqt, 768, 768, nullptr, 0);
    // proj = F_s @ W_lin[layer]  (fp32 to wsTmp)
    gemm128<0><<<dim3(64, 6), 256, 0, stream>>>(wsFs, wsWlt, (void*)wsTmp, nullptr, 1024, 768);
    // F_s_p = normalize(proj) -> out1 (fp32) + wsKV (bf16)
    rownorm_k<<<2048, 256, 0, stream>>>(wsTmp, out1, wsKV);
    kvt_k<<<dim3(64, 3, 32), 256, 0, stream>>>(wsKV, wsKVT);
    // q = F_t @ W_q + b_q  (bf16 to wsQ; reuses wsFs which gemm1 has consumed)
    gemm128<1><<<dim3(64, 6), 256, 0, stream>>>(wsFt, wsWqt, (void*)wsQ, bq, 768, 768);
    // attention -> wsTmp (fp32, pre-residual)
    attn_k<<<512, 256, 0, stream>>>(wsQ, wsKV, wsKVT, wsTmp);
    // out0 = normalize(attn_out + F_t)
    resid_norm_k<<<2048, 256, 0, stream>>>(wsTmp, Ft, out0);
}